// Round 1
// baseline (120.295 us; speedup 1.0000x reference)
//
#include <hip/hip_runtime.h>
#include <hip/hip_bf16.h>
#include <math.h>

#define HID 128
#define NPOS 80
#define NCHAR 256
#define ROWS_PER_BLOCK 8   // batch rows per block
#define RPT 4              // rows per thread (each 128-thread half owns 4 rows)

__global__ __launch_bounds__(256) void tle_kernel(
    const int* __restrict__ msg,
    const float* __restrict__ W1, const float* __restrict__ b1,
    const float* __restrict__ W2, const float* __restrict__ b2,
    const float* __restrict__ W3, const float* __restrict__ b3,
    const float* __restrict__ W4, const float* __restrict__ b4,
    float* __restrict__ out)
{
    const int tid  = threadIdx.x;
    const int j    = tid & (HID - 1);   // hidden index
    const int half = tid >> 7;          // 0 or 1: which 4-row group
    const int b0   = blockIdx.x * ROWS_PER_BLOCK;

    __shared__ int   smsg[ROWS_PER_BLOCK * NPOS];       // 2.5 KB
    __shared__ float sh[ROWS_PER_BLOCK][HID];           // 4 KB

    // Stage message chars for this block's 8 rows (coalesced).
    for (int k = tid; k < ROWS_PER_BLOCK * NPOS; k += 256)
        smsg[k] = msg[b0 * NPOS + k];
    __syncthreads();

    // ---- Layer 1: gather-sum of W1 rows + bias + ELU ----
    float h[RPT];
    const float bias1 = b1[j];
    #pragma unroll
    for (int r = 0; r < RPT; ++r) h[r] = bias1;

    #pragma unroll 4
    for (int p = 0; p < NPOS; ++p) {
        #pragma unroll
        for (int r = 0; r < RPT; ++r) {
            const int row = half * RPT + r;
            const int c = smsg[row * NPOS + p];               // LDS broadcast
            h[r] += W1[(((p << 8) + c) << 7) + j];            // coalesced 256B/wave
        }
    }
    #pragma unroll
    for (int r = 0; r < RPT; ++r) {
        float x = h[r];
        sh[half * RPT + r][j] = x > 0.f ? x : (expf(x) - 1.f);
    }
    __syncthreads();

    // ---- Dense layers 2..4 ----
    const float* Ws[3] = { W2, W3, W4 };
    const float* bs[3] = { b2, b3, b4 };
    #pragma unroll 1
    for (int L = 0; L < 3; ++L) {
        const float* __restrict__ W = Ws[L];
        float acc[RPT];
        const float bv = bs[L][j];
        #pragma unroll
        for (int r = 0; r < RPT; ++r) acc[r] = bv;

        #pragma unroll 4
        for (int i = 0; i < HID; ++i) {
            const float w = W[i * HID + j];                   // reused across 4 rows
            #pragma unroll
            for (int r = 0; r < RPT; ++r)
                acc[r] += sh[half * RPT + r][i] * w;          // LDS broadcast read
        }
        __syncthreads();  // all reads of sh done before overwrite
        #pragma unroll
        for (int r = 0; r < RPT; ++r) {
            float x = acc[r];
            sh[half * RPT + r][j] = x > 0.f ? x : (expf(x) - 1.f);
        }
        __syncthreads();
    }

    // ---- Store ----
    #pragma unroll
    for (int r = 0; r < RPT; ++r) {
        const int row = half * RPT + r;
        out[(b0 + row) * HID + j] = sh[row][j];
    }
}

extern "C" void kernel_launch(void* const* d_in, const int* in_sizes, int n_in,
                              void* d_out, int out_size, void* d_ws, size_t ws_size,
                              hipStream_t stream) {
    const int*   msg = (const int*)  d_in[0];
    const float* W1  = (const float*)d_in[1];
    const float* b1  = (const float*)d_in[2];
    const float* W2  = (const float*)d_in[3];
    const float* b2  = (const float*)d_in[4];
    const float* W3  = (const float*)d_in[5];
    const float* b3  = (const float*)d_in[6];
    const float* W4  = (const float*)d_in[7];
    const float* b4  = (const float*)d_in[8];
    float* out = (float*)d_out;

    const int B = in_sizes[0] / NPOS;          // 8192
    dim3 grid(B / ROWS_PER_BLOCK), block(256);
    tle_kernel<<<grid, block, 0, stream>>>(msg, W1, b1, W2, b2, W3, b3, W4, b4, out);
}